// Round 9
// baseline (252.213 us; speedup 1.0000x reference)
//
#include <hip/hip_runtime.h>

typedef unsigned short u16;
typedef __bf16 bf16x8 __attribute__((ext_vector_type(8)));
typedef float f32x4 __attribute__((ext_vector_type(4)));

union B8 { uint4 u; bf16x8 v; };
union U8 { u16 s[8]; uint4 u; };

#define NB 16
#define NQ 2048
#define NK 2048
#define ND 128

constexpr float CEXP = 0.08838834764831845f * 1.44269504088896340f; // log2e/sqrt(128)
// partial record: O 64x128 f32 (8192) + m(64) + l(64) = 8320 floats
#define PREC 8320
// float offset of partial area in ws (after 16 MB of bf16 K + Vt)
#define PBASE_F 4194304u

template<int C>
__device__ __forceinline__ float dppf(float x) {
  int v = __builtin_bit_cast(int, x);
  int r = __builtin_amdgcn_update_dpp(v, v, C, 0xF, 0xF, true);
  return __builtin_bit_cast(float, r);
}
__device__ __forceinline__ float rowmax16(float x) {
  x = fmaxf(x, dppf<0xB1>(x));
  x = fmaxf(x, dppf<0x4E>(x));
  x = fmaxf(x, dppf<0x141>(x));
  x = fmaxf(x, dppf<0x140>(x));
  return x;
}
__device__ __forceinline__ float rowsum16(float x) {
  x += dppf<0xB1>(x);
  x += dppf<0x4E>(x);
  x += dppf<0x141>(x);
  x += dppf<0x140>(x);
  return x;
}
__device__ __forceinline__ bf16x8 cvt8(float4 a, float4 b) {
  bf16x8 r;
  r[0] = (__bf16)a.x; r[1] = (__bf16)a.y; r[2] = (__bf16)a.z; r[3] = (__bf16)a.w;
  r[4] = (__bf16)b.x; r[5] = (__bf16)b.y; r[6] = (__bf16)b.z; r[7] = (__bf16)b.w;
  return r;
}

// Pre-pass: K fp32 -> bf16 row-major; V fp32 -> bf16 TRANSPOSED d-major [b][d][kv].
__global__ __launch_bounds__(256, 1)
void prepass(const float* __restrict__ kg, const float* __restrict__ vg,
             u16* __restrict__ wsK, u16* __restrict__ wsVt)
{
  const int idx = blockIdx.x;
  const int b  = idx >> 7;
  const int k0 = (idx & 127) << 4;     // 16 kv rows per block
  const int tid = threadIdx.x;

  {
    const float* src = kg + ((size_t)(b * NK + k0)) * ND + tid * 8;
    u16* dst = wsK + ((size_t)(b * NK + k0)) * ND + tid * 8;
    B8 t;
    t.v = cvt8(*(const float4*)src, *(const float4*)(src + 4));
    *(uint4*)dst = t.u;
  }
  {
    const int d = tid & 127, kgr = tid >> 7;
    const float* src = vg + ((size_t)(b * NK + k0 + kgr * 8)) * ND + d;
    U8 t;
    #pragma unroll
    for (int i = 0; i < 8; ++i)
      t.s[i] = __builtin_bit_cast(u16, (__bf16)src[(size_t)i * ND]);
    *(uint4*)(wsVt + ((size_t)(b * ND + d)) * NK + k0 + kgr * 8) = t.u;
  }
}

// Flash attention fwd, split-K=2: 1024 blocks, ALL co-resident (4 blocks/CU).
// 256 thr = 4 waves, Q-tile 64 (16 rows/wave), K-tile 64, K-half = 16 tiles.
// nt<=16: s=0 writes normalized out directly, s=1 exits. nt>16: both write partials.
__global__ __launch_bounds__(256, 4)
void flash_fwd(const float* __restrict__ qg, const u16* __restrict__ wsK,
               const u16* __restrict__ wsVt, const int* __restrict__ vlg,
               float* __restrict__ og, float* __restrict__ wsP)
{
  __shared__ __align__(16) u16 sK[64 * 128];   // row-major, granule^(row&15)
  __shared__ __align__(16) u16 sV[128 * 64];   // d-major,  granule^(d&7)
  __shared__ __align__(16) u16 sP[4][16 * 64]; // per wave, granule^(row&7)

  const int tid  = threadIdx.x;
  const int lane = tid & 63;
  const int wv   = tid >> 6;
  const int n    = lane & 15;
  const int quad = lane >> 4;

  // decode: qt = bi>>5; g = ((bi&7)<<2)|((bi>>3)&3) in [0,32); b = g>>1, s = g&1
  // XCD x hosts batches {2x, 2x+1} (both halves) -> ~2 MB K/V per XCD L2
  const int bi = blockIdx.x;
  const int qt = bi >> 5;
  const int g  = ((bi & 7) << 2) | ((bi >> 3) & 3);
  const int b  = g >> 1;
  const int s  = g & 1;

  const int vl = vlg[b];
  const int nt = (vl + 63) >> 6;
  const bool partial = (nt > 16);

  if (s == 1 && !partial) return;           // empty half, nothing to merge

  const int t0   = s * 16;
  const int tend = min(nt, t0 + 16);

  const int qrow0 = qt * 64 + wv * 16;

  // Q fragments (A-layout A[m=lane&15][k=quad*8+j])
  bf16x8 qf[4];
  #pragma unroll
  for (int c = 0; c < 4; ++c) {
    const float* qp = qg + (size_t)(b * NQ + qrow0 + n) * ND + c * 32 + quad * 8;
    qf[c] = cvt8(*(const float4*)qp, *(const float4*)(qp + 4));
  }

  f32x4 O[8];
  float mst[4], lst[4];
  #pragma unroll
  for (int f = 0; f < 8; ++f) O[f] = (f32x4){0.f, 0.f, 0.f, 0.f};
  #pragma unroll
  for (int r = 0; r < 4; ++r) { mst[r] = -__builtin_inff(); lst[r] = 0.f; }

  const u16* kb  = wsK  + (size_t)(b * NK) * ND;
  const u16* vtb = wsVt + (size_t)(b * ND) * NK;

  uint4 kreg[4], vreg[4];
  auto kvload = [&](int t) {
    const u16* ks = kb + (size_t)(t * 64) * ND;
    #pragma unroll
    for (int c = 0; c < 4; ++c)
      kreg[c] = *(const uint4*)(ks + (c * 16 + (tid >> 4)) * 128 + (tid & 15) * 8);
    const u16* vs = vtb + t * 64;
    #pragma unroll
    for (int c = 0; c < 4; ++c)
      vreg[c] = *(const uint4*)(vs + (size_t)(c * 32 + (tid >> 3)) * NK + (tid & 7) * 8);
  };
  auto kvstore = [&]() {
    #pragma unroll
    for (int c = 0; c < 4; ++c) {
      int row = c * 16 + (tid >> 4);
      *(uint4*)(&sK[row * 128 + (((tid & 15) ^ (row & 15)) << 3)]) = kreg[c];
    }
    #pragma unroll
    for (int c = 0; c < 4; ++c) {
      int d = c * 32 + (tid >> 3);
      *(uint4*)(&sV[d * 64 + (((tid & 7) ^ (d & 7)) << 3)]) = vreg[c];
    }
  };

  kvload(t0);
  kvstore();

  u16* Pw = sP[wv];

  for (int t = t0; t < tend; ++t) {
    __syncthreads();                     // tile t visible in LDS
    if (t + 1 < tend) kvload(t + 1);     // global -> regs, overlaps compute

    // ---- S = Q K^T ----
    f32x4 Sv[4];
    #pragma unroll
    for (int jn = 0; jn < 4; ++jn) Sv[jn] = (f32x4){0.f, 0.f, 0.f, 0.f};
    #pragma unroll
    for (int c = 0; c < 4; ++c)
      #pragma unroll
      for (int jn = 0; jn < 4; ++jn) {
        B8 bb;
        bb.u = *(const uint4*)(&sK[(jn * 16 + n) * 128 + (((c * 4 + quad) ^ n) << 3)]);
        Sv[jn] = __builtin_amdgcn_mfma_f32_16x16x32_bf16(qf[c], bb.v, Sv[jn], 0, 0, 0);
      }

    // ---- mask tail (kv >= vl) ----
    if (t * 64 + 64 > vl) {
      #pragma unroll
      for (int jn = 0; jn < 4; ++jn) {
        bool msk = (t * 64 + jn * 16 + n) >= vl;
        #pragma unroll
        for (int r = 0; r < 4; ++r)
          Sv[jn][r] = msk ? -1e30f : Sv[jn][r];
      }
    }

    // ---- online softmax ----
    float al[4];
    #pragma unroll
    for (int r = 0; r < 4; ++r) {
      float mx = fmaxf(fmaxf(Sv[0][r], Sv[1][r]), fmaxf(Sv[2][r], Sv[3][r]));
      mx = rowmax16(mx);
      float mnew = fmaxf(mst[r], mx);
      float a = __builtin_exp2f((mst[r] - mnew) * CEXP);
      mst[r] = mnew;
      float ssum = 0.f;
      #pragma unroll
      for (int jn = 0; jn < 4; ++jn) {
        float p = __builtin_exp2f((Sv[jn][r] - mnew) * CEXP);
        Sv[jn][r] = p;
        ssum += p;
      }
      ssum = rowsum16(ssum);
      lst[r] = lst[r] * a + ssum;
      al[r] = a;
    }
    #pragma unroll
    for (int f = 0; f < 8; ++f) {
      O[f][0] *= al[0]; O[f][1] *= al[1]; O[f][2] *= al[2]; O[f][3] *= al[3];
    }

    // P (C-layout) -> per-wave LDS (granule-XOR); same-wave DS in-order => safe
    #pragma unroll
    for (int jn = 0; jn < 4; ++jn)
      #pragma unroll
      for (int r = 0; r < 4; ++r) {
        int row = quad * 4 + r;
        __bf16 h = (__bf16)Sv[jn][r];
        Pw[row * 64 + (((jn * 2 + (n >> 3)) ^ (row & 7)) << 3) + (n & 7)]
            = __builtin_bit_cast(u16, h);
      }

    // ---- O += P V ----
    #pragma unroll
    for (int kc = 0; kc < 2; ++kc) {
      B8 ta;
      ta.u = *(const uint4*)(&Pw[n * 64 + (((kc * 4 + quad) ^ (n & 7)) << 3)]);
      bf16x8 af = ta.v;
      #pragma unroll
      for (int f = 0; f < 8; ++f) {
        int d = f * 16 + n;
        B8 bb;
        bb.u = *(const uint4*)(&sV[d * 64 + (((kc * 4 + quad) ^ (d & 7)) << 3)]);
        O[f] = __builtin_amdgcn_mfma_f32_16x16x32_bf16(af, bb.v, O[f], 0, 0, 0);
      }
    }

    __syncthreads();                     // all waves done reading tile t
    if (t + 1 < tend) kvstore();
  }

  if (!partial) {
    // whole batch fit in this half: normalized direct output
    #pragma unroll
    for (int r = 0; r < 4; ++r) {
      float rl = 1.0f / lst[r];
      int qrow = qrow0 + quad * 4 + r;
      float* op = og + (size_t)(b * NQ + qrow) * ND + n;
      #pragma unroll
      for (int f = 0; f < 8; ++f)
        op[f * 16] = O[f][r] * rl;
    }
  } else {
    const size_t pbase = PBASE_F + ((size_t)(b * 32 + qt) * 2 + s) * PREC;
    #pragma unroll
    for (int r = 0; r < 4; ++r) {
      int row = wv * 16 + quad * 4 + r;
      float* op = wsP + pbase + row * 128 + n;
      #pragma unroll
      for (int f = 0; f < 8; ++f)
        op[f * 16] = O[f][r];
      if (n == 0) {
        wsP[pbase + 8192 + row] = mst[r];
        wsP[pbase + 8256 + row] = lst[r];
      }
    }
  }
}

// Merge the two K-half partials for (b,qt) pairs with nt > 16.
__global__ __launch_bounds__(256, 1)
void merge2(const float* __restrict__ wsP, const int* __restrict__ vlg,
            float* __restrict__ og)
{
  const int bq = blockIdx.x;           // b*32 + qt
  const int b  = bq >> 5, qt = bq & 31;
  const int vl = vlg[b];
  if (((vl + 63) >> 6) <= 16) return;  // handled directly by flash_fwd

  const int tid = threadIdx.x;
  const int row = tid >> 2, dq = tid & 3;

  const size_t base0 = PBASE_F + (size_t)bq * 2 * PREC;
  const size_t base1 = base0 + PREC;

  float m0 = wsP[base0 + 8192 + row];
  float m1 = wsP[base1 + 8192 + row];
  float m  = fmaxf(m0, m1);
  float w0 = __builtin_exp2f((m0 - m) * CEXP);
  float w1 = __builtin_exp2f((m1 - m) * CEXP);
  float den = w0 * wsP[base0 + 8256 + row] + w1 * wsP[base1 + 8256 + row];
  float rd = 1.0f / den;

  const float* p0 = wsP + base0 + row * 128 + dq * 32;
  const float* p1 = wsP + base1 + row * 128 + dq * 32;
  float* out = og + (size_t)(b * NQ + qt * 64 + row) * ND + dq * 32;
  #pragma unroll
  for (int i = 0; i < 8; ++i) {
    float4 a = *(const float4*)(p0 + i * 4);
    float4 c = *(const float4*)(p1 + i * 4);
    float4 o;
    o.x = (w0 * a.x + w1 * c.x) * rd;
    o.y = (w0 * a.y + w1 * c.y) * rd;
    o.z = (w0 * a.z + w1 * c.z) * rd;
    o.w = (w0 * a.w + w1 * c.w) * rd;
    *(float4*)(out + i * 4) = o;
  }
}

extern "C" void kernel_launch(void* const* d_in, const int* in_sizes, int n_in,
                              void* d_out, int out_size, void* d_ws, size_t ws_size,
                              hipStream_t stream) {
  const float* q  = (const float*)d_in[0];
  const float* k  = (const float*)d_in[1];
  const float* v  = (const float*)d_in[2];
  const int*  vl  = (const int*)d_in[3];
  float* out = (float*)d_out;

  u16* wsK  = (u16*)d_ws;                        // 8 MB
  u16* wsVt = wsK + (size_t)NB * NK * ND;        // 8 MB
  float* wsP = (float*)d_ws;                     // partials at PBASE_F floats
  // total ws use: 16 MB + 34.1 MB = 50.1 MB (ws >= 68 MB proven in R6)

  hipLaunchKernelGGL(prepass, dim3(NB * (NK / 16)), dim3(256), 0, stream, k, v, wsK, wsVt);
  hipLaunchKernelGGL(flash_fwd, dim3(1024), dim3(256), 0, stream, q, wsK, wsVt, vl, out, wsP);
  hipLaunchKernelGGL(merge2, dim3(512), dim3(256), 0, stream, wsP, vl, out);
}